// Round 14
// baseline (395.193 us; speedup 1.0000x reference)
//
#include <hip/hip_runtime.h>
#include <cstdint>
#include <cstddef>

// ---------------------------------------------------------------------------
// Episodic memory module (DMN) on MI355X — round 20.
//
// R19 post-mortem: 2-barrier scan = null (63.4->63.0us) — barriers weren't
// the cost; all 16 waves traverse the same serial chain so the lockstep
// structure dominates.  scan plateaued across 4 structures; parked.
// Remaining big item: scores_fixed (48us standalone) whose inputs all live
// in xproj's WGs (same (b,s)->64-row mapping; reads the ff_ws bytes xproj
// just wrote; xproj VALUBusy ~10% = idle capacity).
//
// R20: fold scores_fixed into xproj's tail.  After the main loop (acc dead,
// 32 AGPRs freed), 8 waves split 4 M-tiles x 4 col-tiles as
// (mtL0=(w>>2)*2, ntq=w&3) — HALF the per-wave work of the standalone
// 4-wave kernel.  __syncthreads() (vmcnt drain) makes ff_ws visible;
// formula bit-identical (pfix = accq+b1; ep0 score = tanh(pfix+accm)*W2).
// scores_fixed kernel deleted.
// Predictions: -48us dispatch, xproj 66->~85, VGPR 64, WRITE ~137MB
// (+16MB pfix), absmax 0.0078125 exact.  Tripwires: WRITE>160MB or
// VGPR<64 (spill) or xproj>95us -> revert.
// ---------------------------------------------------------------------------

typedef __bf16 bf16_t;
typedef __attribute__((ext_vector_type(8))) __bf16 bf16x8;
typedef __attribute__((ext_vector_type(4))) __bf16 bf16x4;
typedef __attribute__((ext_vector_type(4))) float f32x4;

static __device__ __forceinline__ f32x4 mfma16(bf16x8 a, bf16x8 b, f32x4 c) {
  return __builtin_amdgcn_mfma_f32_16x16x32_bf16(a, b, c, 0, 0, 0);
}
static __device__ __forceinline__ float fast_rcp(float x) { return __builtin_amdgcn_rcpf(x); }
static __device__ __forceinline__ float sigmoid_f(float x) {
  return fast_rcp(1.f + exp2f(-1.44269504f * x));
}
static __device__ __forceinline__ float tanh_f(float x) {
  float e = exp2f(2.88539008f * x);
  return 1.f - 2.f * fast_rcp(e + 1.f);
}
static __device__ __forceinline__ unsigned short f2bf(float x) {
  __bf16 h = (__bf16)x;
  return __builtin_bit_cast(unsigned short, h);
}
// Workgroup barrier WITHOUT the vmcnt(0) drain __syncthreads() carries.
// All call sites are in wave-uniform control flow.
static __device__ __forceinline__ void ldsbar() {
  asm volatile("s_waitcnt lgkmcnt(0)\n\ts_barrier" ::: "memory");
}
// Opaque pin: value becomes an asm output — cannot be rematerialized or its
// defining load sunk past this point.  Zero instructions emitted.
static __device__ __forceinline__ void pin_frag(bf16x8& v) {
  f32x4 t = __builtin_bit_cast(f32x4, v);
  asm volatile("" : "+v"(t));
  v = __builtin_bit_cast(bf16x8, t);
}

// ws layout (bf16 element offsets).  B-fragment layout for a K x N matrix:
// elem(k,n) at ((kt*NT + nt)*64 + lane)*8 + j, kt=k/32, nt=n/16,
// lane=((k%32)/8)*16 + (n%16), j=k%8.
static constexpr size_t E_GRUK  = 0;                            // K=256 N=512
static constexpr size_t E_RKR   = 131072;                       // K=256 N=256
static constexpr size_t E_RKH   = 196608;
static constexpr size_t E_W1F   = 262144;                       // K=1024 N=64
static constexpr size_t E_WMF   = 327680;                       // K=768 N=256
static constexpr size_t E_XR    = 524288;                       // + b*131072 (A-frag)
static constexpr size_t E_XHC   = E_XR  + (size_t)128 * 131072; // + b*131072 (C order)
static constexpr size_t E_FACTS = E_XHC + (size_t)128 * 131072; // + b*131072 (A-frag)
static constexpr size_t E_END   = E_FACTS + (size_t)128 * 131072;
static constexpr size_t F_SCORES = 0;
static constexpr size_t F_MEM    = 65536;
static constexpr size_t F_PFIX   = 131072;   // 128*32*4*64 f32x4 = 4M floats

__global__ void prep_weights(const float* __restrict__ gru_k,
                             const float* __restrict__ gru_rk,
                             const float* __restrict__ W1,
                             const float* __restrict__ Wm,
                             bf16_t* __restrict__ ws) {
  size_t idx = (size_t)blockIdx.x * 256 + threadIdx.x;
  if (idx >= 524288) return;
  size_t local; int NT, which;
  if (idx < 131072)      { local = idx;          NT = 32; which = 0; }
  else if (idx < 196608) { local = idx - 131072; NT = 16; which = 1; }
  else if (idx < 262144) { local = idx - 196608; NT = 16; which = 2; }
  else if (idx < 327680) { local = idx - 262144; NT = 4;  which = 3; }
  else                   { local = idx - 327680; NT = 16; which = 4; }
  int j    = (int)(local & 7);
  int lane = (int)((local >> 3) & 63);
  size_t rem = local >> 9;
  int nt = (int)(rem % NT);
  int kt = (int)(rem / NT);
  int k = kt * 32 + (lane >> 4) * 8 + j;
  int n = nt * 16 + (lane & 15);
  float v;
  switch (which) {
    case 0:  v = gru_k[(size_t)k * 768 + 256 + n]; break;
    case 1:  v = gru_rk[(size_t)k * 768 + 256 + n]; break;
    case 2:  v = gru_rk[(size_t)k * 768 + 512 + n]; break;
    case 3:  v = (n < 50) ? W1[(size_t)k * 50 + n] : 0.f; break;
    default: v = Wm[(size_t)k * 256 + n]; break;
  }
  ws[idx] = (__bf16)v;
}

// ------------------------------- kernel A ----------------------------------
// x_proj = facts[b] @ gru_k[:,U:3U] + bias; persists facts bf16 A-frags;
// R20: fused scores_fixed tail — pfix (q-terms + b1 in C-frag order) AND
// episode-0 scores (mem==question at ep0) for rows [64s,64s+64).
// grid (b=128, s=8), 512 threads (8 waves).  Main loop unchanged from R8.
// (512,4): allocator-compatible optimum — VGPR 64, no spills.
__global__ __launch_bounds__(512, 4)
void xproj_kernel(const float* __restrict__ facts,
                  const float* __restrict__ question,
                  const float* __restrict__ gru_bg,
                  const float* __restrict__ b1g,
                  const float* __restrict__ W2g,
                  const float* __restrict__ b2g,
                  bf16_t* __restrict__ ws,
                  float* __restrict__ mem_ws,
                  float* __restrict__ pfix,
                  float* __restrict__ scores_ws) {
  const int b = blockIdx.x, s = blockIdx.y;
  const int tid = threadIdx.x, w = tid >> 6, lane = tid & 63;
  const int quad = lane >> 4, col = lane & 15;
  __shared__ float grub[512];
  __shared__ float q_lds[256], b1_lds[64], W2_lds[64], score_lds[64];
  __shared__ float b2s;
  __shared__ bf16_t fragbuf[8192];   // 2 tiles; logical unit u at u^kt (swizzled)
  __shared__ bf16_t xrtrans[8192];   // 2 tiles; logical unit u at u^((u>>4)&3)
  grub[tid] = gru_bg[256 + tid];     // [0,256)=xr bias, [256,512)=xh bias
  if (tid < 256) q_lds[tid] = question[(size_t)b * 256 + tid];
  if (tid < 64) {
    b1_lds[tid] = (tid < 50) ? b1g[tid] : 0.f;
    W2_lds[tid] = (tid < 50) ? W2g[tid] : 0.f;
  }
  if (tid == 0) b2s = b2g[0];
  if (s == 0 && tid < 256) mem_ws[b * 256 + tid] = question[(size_t)b * 256 + tid];
  __syncthreads();

  bf16_t* xr_ws = ws + E_XR   + (size_t)b * 131072;
  bf16_t* xh_ws = ws + E_XHC  + (size_t)b * 131072;
  bf16_t* ff_ws = ws + E_FACTS + (size_t)b * 131072;
  const bf16_t* gbase = ws + E_GRUK;
  // staging ownership: 512 threads cover 2 tiles x 16 rows x 16 col-segs
  const int tile = tid >> 8, row = (tid >> 4) & 15, cseg = tid & 15;

  // this thread's two swizzled fragbuf deposit units (constant across iters)
  int wunit[2];
  #pragma unroll
  for (int half = 0; half < 2; ++half) {
    int u0 = cseg * 16 + half * 8;
    int kt = u0 >> 5, qk = (u0 >> 3) & 3;
    int u = kt * 64 + qk * 16 + row;
    wunit[half] = tile * 512 + (u ^ kt);
  }

  for (int it = 0; it < 2; ++it) {
    const int Mt0 = s * 4 + 2 * it;
    // stage this thread's 16 facts floats (one tile each; 512 thr = 2 tiles)
    float v[16];
    {
      const float* src = facts + (((size_t)b * 512) + (Mt0 + tile) * 16 + row) * 256 + cseg * 16;
      #pragma unroll
      for (int i = 0; i < 4; ++i) {
        f32x4 t4 = ((const f32x4*)src)[i];
        v[4*i] = t4[0]; v[4*i+1] = t4[1]; v[4*i+2] = t4[2]; v[4*i+3] = t4[3];
      }
    }
    #pragma unroll
    for (int half = 0; half < 2; ++half) {
      bf16x8 pk;
      #pragma unroll
      for (int j = 0; j < 8; ++j) pk[j] = (__bf16)v[half * 8 + j];
      *(bf16x8*)&fragbuf[wunit[half] * 8] = pk;
    }
    ldsbar();  // bar1: fragbuf visible
    { // persist facts frags for scores (unswizzle -> ws holds logical layout)
      #pragma unroll
      for (int e = 0; e < 2; ++e) {
        int p = 2 * tid + e;
        int t = p >> 9, pu = p & 511;
        int qu = pu ^ (pu >> 6);
        bf16x8 f = *(bf16x8*)&fragbuf[(t * 512 + qu) * 8];
        *(bf16x8*)(ff_ws + (size_t)(Mt0 + t) * 4096 + (size_t)pu * 8) = f;
      }
    }
    // paired MFMA: each gk fragment load feeds BOTH A-tiles; wave owns nt=4
    f32x4 acc[2][4];
    #pragma unroll
    for (int t = 0; t < 2; ++t)
      #pragma unroll
      for (int nt = 0; nt < 4; ++nt) acc[t][nt] = (f32x4){0.f, 0.f, 0.f, 0.f};
    #pragma unroll
    for (int kt = 0; kt < 8; ++kt) {
      int us = (kt * 64 + lane) ^ kt;
      bf16x8 af0 = *(const bf16x8*)&fragbuf[(size_t)us * 8];
      bf16x8 af1 = *(const bf16x8*)&fragbuf[(size_t)(512 + us) * 8];
      #pragma unroll
      for (int nt = 0; nt < 4; ++nt) {
        bf16x8 g = *(const bf16x8*)(gbase + (((size_t)kt * 32 + (w * 4 + nt)) * 64 + lane) * 8);
        acc[0][nt] = mfma16(af0, g, acc[0][nt]);
        acc[1][nt] = mfma16(af1, g, acc[1][nt]);
      }
    }
    // epilogue: waves 0-3 -> xr (transpose via swizzled LDS), 4-7 -> xh
    #pragma unroll
    for (int t = 0; t < 2; ++t)
      #pragma unroll
      for (int nt = 0; nt < 4; ++nt) {
        int o = w * 64 + nt * 16 + col;
        float bias = grub[o];
        if (o < 256) { // wave-uniform: w < 4
          int ktA = o >> 5, qkA = (o >> 3) & 3, j = o & 7;
          #pragma unroll
          for (int r = 0; r < 4; ++r) {
            int u = ktA * 64 + qkA * 16 + (quad * 4 + r);
            int us2 = u ^ ((u >> 4) & 3);
            xrtrans[(t * 512 + us2) * 8 + j] = (__bf16)(acc[t][nt][r] + bias);
          }
        } else {       // wave-uniform: w >= 4
          int ntx = (o >> 4) - 16;
          unsigned short s0 = f2bf(acc[t][nt][0] + bias), s1 = f2bf(acc[t][nt][1] + bias);
          unsigned short s2 = f2bf(acc[t][nt][2] + bias), s3 = f2bf(acc[t][nt][3] + bias);
          uint2 pv;
          pv.x = (unsigned)s0 | ((unsigned)s1 << 16);
          pv.y = (unsigned)s2 | ((unsigned)s3 << 16);
          *(uint2*)(xh_ws + ((size_t)(Mt0 + t) * 16 + ntx) * 256 + lane * 4) = pv;
        }
      }
    ldsbar();  // bar2: xrtrans visible
    { // xr store: read swizzled, write logical (ws layout unchanged for scan)
      #pragma unroll
      for (int e = 0; e < 2; ++e) {
        int p = 2 * tid + e;
        int t = p >> 9, pu = p & 511;
        int qu = pu ^ ((pu >> 4) & 3);
        bf16x8 f = *(bf16x8*)&xrtrans[(t * 512 + qu) * 8];
        *(bf16x8*)(xr_ws + (size_t)(Mt0 + t) * 4096 + (size_t)pu * 8) = f;
      }
    }
    // no bar3: next iteration's bar1 orders xrtrans reads vs next writes.
  }

  // ---- fused scores_fixed tail: pfix + ep0 scores for rows [64s,64s+64) ---
  // Wave w: col-tile ntq=w&3, local M-tiles {mtL0, mtL0+1} with mtL0=(w>>2)*2.
  // Formula bit-identical to the old scores_fixed kernel (same f8 from ff_ws,
  // same q, same W1 frags): pfix = accq+b1; ep0 score = tanh(pfix+accm)*W2.
  __syncthreads();              // drains vmcnt: ff_ws stores from ALL waves
  if (tid < 64) score_lds[tid] = b2s;
  ldsbar();                     // score_lds init visible before atomics
  {
    const int ntq = w & 3;
    const int mtL0 = (w >> 2) * 2;
    const bf16_t* ffb = ff_ws + (size_t)(s * 4 + mtL0) * 4096;
    const bf16_t* w1b = ws + E_W1F;

    f32x4 accq[2], accm[2];
    #pragma unroll
    for (int m2 = 0; m2 < 2; ++m2) {
      accq[m2] = (f32x4){0.f, 0.f, 0.f, 0.f};
      accm[m2] = (f32x4){0.f, 0.f, 0.f, 0.f};
    }
    #pragma unroll 2
    for (int kt = 0; kt < 8; ++kt) {
      bf16x8 wf0 = *(const bf16x8*)(w1b + (((size_t)(kt)      * 4 + ntq) * 64 + lane) * 8);
      bf16x8 wf1 = *(const bf16x8*)(w1b + (((size_t)(8  + kt) * 4 + ntq) * 64 + lane) * 8);
      bf16x8 wf2 = *(const bf16x8*)(w1b + (((size_t)(16 + kt) * 4 + ntq) * 64 + lane) * 8);
      bf16x8 wf3 = *(const bf16x8*)(w1b + (((size_t)(24 + kt) * 4 + ntq) * 64 + lane) * 8);
      const f32x4* qp = (const f32x4*)&q_lds[kt * 32 + quad * 8];
      f32x4 qa = qp[0], qb = qp[1];
      float qv[8] = {qa[0],qa[1],qa[2],qa[3],qb[0],qb[1],qb[2],qb[3]};
      #pragma unroll
      for (int m2 = 0; m2 < 2; ++m2) {
        bf16x8 f8 = *(const bf16x8*)(ffb + (size_t)m2 * 4096 + (kt * 64 + lane) * 8);
        bf16x8 a0, a2;
        #pragma unroll
        for (int j = 0; j < 8; ++j) {
          float fu = (float)f8[j];
          a0[j] = (__bf16)(fu * qv[j]);
          a2[j] = (__bf16)fabsf(fu - qv[j]);
        }
        accq[m2] = mfma16(a0, wf0, accq[m2]);
        accq[m2] = mfma16(a2, wf2, accq[m2]);
        accm[m2] = mfma16(a0, wf1, accm[m2]);
        accm[m2] = mfma16(a2, wf3, accm[m2]);
      }
    }
    int hcol = ntq * 16 + col;
    float pb1 = b1_lds[hcol], pw2 = W2_lds[hcol];
    f32x4* po = (f32x4*)pfix;
    #pragma unroll
    for (int m2 = 0; m2 < 2; ++m2) {
      // pfix = q-terms + b1 (the later-episode accumulator seed)
      f32x4 o = accq[m2];
      #pragma unroll
      for (int r = 0; r < 4; ++r) o[r] += pb1;
      po[(((size_t)b * 32 + s * 4 + mtL0 + m2) * 4 + ntq) * 64 + lane] = o;
      // ep0 score partial: tanh(pfix + m-terms) * W2  (mem==q at ep0)
      float p[4];
      #pragma unroll
      for (int r = 0; r < 4; ++r) p[r] = tanh_f(o[r] + accm[m2][r]) * pw2;
      #pragma unroll
      for (int r = 0; r < 4; ++r) {
        p[r] += __shfl_xor(p[r], 1, 64);
        p[r] += __shfl_xor(p[r], 2, 64);
        p[r] += __shfl_xor(p[r], 4, 64);
        p[r] += __shfl_xor(p[r], 8, 64);
      }
      if (col == 0) {
        #pragma unroll
        for (int r = 0; r < 4; ++r)
          atomicAdd(&score_lds[(mtL0 + m2) * 16 + quad * 4 + r], p[r]);
      }
    }
  }
  ldsbar();                     // all atomics done
  if (tid < 64) scores_ws[(size_t)b * 512 + s * 64 + tid] = score_lds[tid];
}

// ------------------------------- kernel B ----------------------------------
// scores[b, n] for episodes 1,2: m-terms only on top of P_fixed.
// grid (b=128, s=8); WG does rows [64s,64s+64).  (R10-proven, ~34us)
__global__ __launch_bounds__(256)
void scores_kernel(const float* __restrict__ W2g,
                   const float* __restrict__ b2g,
                   const bf16_t* __restrict__ ws,
                   const float* __restrict__ mem_ws,
                   const float* __restrict__ pfix,
                   float* __restrict__ scores_ws) {
  const int b = blockIdx.x, s = blockIdx.y;
  const int tid = threadIdx.x, w = tid >> 6, lane = tid & 63;
  const int quad = lane >> 4, col = lane & 15;
  __shared__ float mem_lds[256], W2_lds[64], score_lds[64];
  __shared__ float b2s;
  mem_lds[tid] = mem_ws[(size_t)b * 256 + tid];
  if (tid < 64) W2_lds[tid] = (tid < 50) ? W2g[tid] : 0.f;
  if (tid == 0) b2s = b2g[0];
  __syncthreads();
  if (tid < 64) score_lds[tid] = b2s;
  __syncthreads();

  const bf16_t* ffb = ws + E_FACTS + (size_t)b * 131072 + (size_t)s * 4 * 4096;
  const bf16_t* w1b = ws + E_W1F;
  const f32x4* pf = (const f32x4*)pfix;

  f32x4 acc[4];
  #pragma unroll
  for (int mt = 0; mt < 4; ++mt)
    acc[mt] = pf[(((size_t)b * 32 + s * 4 + mt) * 4 + w) * 64 + lane];

  #pragma unroll 2
  for (int kt = 0; kt < 8; ++kt) {
    bf16x8 wf1 = *(const bf16x8*)(w1b + (((size_t)(8  + kt) * 4 + w) * 64 + lane) * 8);
    bf16x8 wf3 = *(const bf16x8*)(w1b + (((size_t)(24 + kt) * 4 + w) * 64 + lane) * 8);
    const f32x4* mp = (const f32x4*)&mem_lds[kt * 32 + quad * 8];
    f32x4 ma = mp[0], mb = mp[1];
    float mv[8] = {ma[0],ma[1],ma[2],ma[3],mb[0],mb[1],mb[2],mb[3]};
    #pragma unroll
    for (int mt = 0; mt < 4; ++mt) {
      bf16x8 f8 = *(const bf16x8*)(ffb + (size_t)mt * 4096 + (kt * 64 + lane) * 8);
      bf16x8 a1, a3;
      #pragma unroll
      for (int j = 0; j < 8; ++j) {
        float fu = (float)f8[j];
        a1[j] = (__bf16)(fu * mv[j]);
        a3[j] = (__bf16)fabsf(fu - mv[j]);
      }
      acc[mt] = mfma16(a1, wf1, acc[mt]);
      acc[mt] = mfma16(a3, wf3, acc[mt]);
    }
  }
  int hcol = w * 16 + col;
  float pw2 = W2_lds[hcol];
  #pragma unroll
  for (int mt = 0; mt < 4; ++mt) {
    float p[4];
    #pragma unroll
    for (int r = 0; r < 4; ++r) p[r] = tanh_f(acc[mt][r]) * pw2;
    #pragma unroll
    for (int r = 0; r < 4; ++r) {
      p[r] += __shfl_xor(p[r], 1, 64);
      p[r] += __shfl_xor(p[r], 2, 64);
      p[r] += __shfl_xor(p[r], 4, 64);
      p[r] += __shfl_xor(p[r], 8, 64);
    }
    if (col == 0) {
      #pragma unroll
      for (int r = 0; r < 4; ++r)
        atomicAdd(&score_lds[mt * 16 + quad * 4 + r], p[r]);
    }
  }
  __syncthreads();
  if (tid < 64) scores_ws[(size_t)b * 512 + s * 64 + tid] = score_lds[tid];
}

// ------------------------------- kernel C ----------------------------------
// softmax + chunked-Picard attn-GRU scan (T=32, 16 chunks) + memory update.
// 128 WGs x 1024 threads (16 waves = 4/SIMD).
// R19 roles: S1/S2 by (kf=w>>1, mts=w&1); S3/blend by OUTPUT COLUMN nt=w —
// wave computes BOTH M-tiles for cols [16w,16w+16), owns h cols end-to-end.
// 2 barriers/chunk.  R16 (kept): waves_per_eu(4,4) + asm pin on fr.
__global__
__attribute__((amdgpu_flat_work_group_size(1024, 1024), amdgpu_waves_per_eu(4, 4)))
void scan_kernel(const float* __restrict__ question,
                 const float* __restrict__ bmg,
                 const bf16_t* __restrict__ ws,
                 const float* __restrict__ scores_ws,
                 float* __restrict__ mem_ws,
                 float* __restrict__ out,
                 int last) {
  const int b = blockIdx.x;
  const int tid = threadIdx.x, w = tid >> 6, lane = tid & 63;
  const int quad = lane >> 4, col = lane & 15;
  const int kf = w >> 1, mts = w & 1;   // S1/S2 roles; S3/blend role: nt = w

  __shared__ bf16_t hb_lds[512];        // bf16 h ping-pong [0,256) / [256,512)
  __shared__ float aw_lds[512], pt_lds[16];
  __shared__ float q_lds[256], mem_lds[256], bm_lds[256], red[16];
  __shared__ bf16_t fragbuf[8192];      // rh A-frags, 2 M-tiles x 4096
  __shared__ bf16_t rkh_lds[65536];     // rkh B-frags, 128KB, staged once

  // stage rkh frags global->LDS, stride-1 per lane (conflict-free, coalesced)
  // 8192 bf16x8 units / 1024 threads = 8 iterations.
  {
    const bf16x8* srcw = (const bf16x8*)(ws + E_RKH);
    bf16x8* dstw = (bf16x8*)rkh_lds;
    #pragma unroll
    for (int i = 0; i < 8; ++i)
      dstw[(size_t)i * 1024 + tid] = srcw[(size_t)i * 1024 + tid];
  }

  if (tid < 256) {
    q_lds[tid]   = question[(size_t)b * 256 + tid];
    mem_lds[tid] = mem_ws[(size_t)b * 256 + tid];
    bm_lds[tid]  = bmg[tid];
  }
  if (tid < 512) hb_lds[tid] = (__bf16)0.f;

  // softmax over 512 scores: waves 0-7 (tid<512) do the work, barriers global
  float s0 = 0.f, e0 = 0.f;
  if (tid < 512) {
    s0 = scores_ws[(size_t)b * 512 + tid];
    float mx = s0;
    #pragma unroll
    for (int o = 32; o > 0; o >>= 1) mx = fmaxf(mx, __shfl_xor(mx, o, 64));
    if (lane == 0) red[w] = mx;
  }
  __syncthreads();
  if (tid < 512) {
    float gmax = red[0];
    #pragma unroll
    for (int i = 1; i < 8; ++i) gmax = fmaxf(gmax, red[i]);
    e0 = __expf(s0 - gmax);
    float sm = e0;
    #pragma unroll
    for (int o = 32; o > 0; o >>= 1) sm += __shfl_xor(sm, o, 64);
    if (lane == 0) red[8 + w] = sm;
  }
  __syncthreads();
  if (tid < 512) {
    float tot = red[8];
    #pragma unroll
    for (int i = 9; i < 16; ++i) tot += red[i];
    aw_lds[tid] = e0 * fast_rcp(tot);
  }
  ldsbar();
  // per-chunk (T=32) blend weights in place:
  // aw[s] := a_s * prod_{j>s in chunk}(1-a_j),  pt[ct] := prod(1-a) over chunk
  if (tid < 16) {
    float av[32];
    #pragma unroll
    for (int j = 0; j < 32; ++j) av[j] = aw_lds[tid * 32 + j];
    float suf = 1.f;
    #pragma unroll
    for (int j = 31; j >= 0; --j) {
      aw_lds[tid * 32 + j] = av[j] * suf;
      suf *= (1.f - av[j]);
    }
    pt_lds[tid] = suf;
  }
  ldsbar();  // also covers rkh_lds staging visibility (lgkmcnt drains ds_writes)

  // S1 recurrence weights: kf owns rkr out-cols [32kf, 32kf+32); 64 VGPR.
  // Duplicated across the mts pair (both waves run S1).  Pinned in registers
  // via opaque asm so the loads cannot be sunk into the chunk loop.
  const bf16_t* xrb = ws + E_XR  + (size_t)b * 131072;
  const bf16_t* xhb = ws + E_XHC + (size_t)b * 131072;
  bf16x8 fr[2][8];
  {
    const bf16_t* rb = ws + E_RKR;
    #pragma unroll
    for (int nt_ = 0; nt_ < 2; ++nt_)
      #pragma unroll
      for (int kt = 0; kt < 8; ++kt) {
        size_t off = (((size_t)kt * 16 + (kf * 2 + nt_)) * 64 + lane) * 8;
        fr[nt_][kt] = *(const bf16x8*)(rb + off);
      }
    #pragma unroll
    for (int nt_ = 0; nt_ < 2; ++nt_)
      #pragma unroll
      for (int kt = 0; kt < 8; ++kt)
        pin_frag(fr[nt_][kt]);
  }
  // chunk-0 xr (A-frag of tile mts, fragment kf) and xh (C order, both mt,
  // ntx = w — this wave's output col group)
  bf16x8 xf_c;
  bf16x4 xh_c[2];
  xf_c = *(const bf16x8*)(xrb + (size_t)mts * 4096 + ((size_t)kf * 64 + lane) * 8);
  #pragma unroll
  for (int mt = 0; mt < 2; ++mt)
    xh_c[mt] = *(const bf16x4*)(xhb + ((size_t)mt * 16 + w) * 256 + lane * 4);

  bf16_t* hbc = &hb_lds[0];
  bf16_t* hbn = &hb_lds[256];
  float hs = 0.f;  // exact fp32 self-copy of this wave's h cols [16w,16w+16)

  for (int ct = 0; ct < 16; ++ct) {
    // S1: rv0 = h @ rkr (both mts waves duplicate).  Split-K 2 chains of 4.
    f32x4 z = (f32x4){0.f,0.f,0.f,0.f};
    f32x4 a0a = z, a0b = z, a1a = z, a1b = z;
    #pragma unroll
    for (int kt = 0; kt < 4; ++kt) {
      bf16x8 hf = *(const bf16x8*)&hbc[kt * 32 + quad * 8];
      a0a = mfma16(hf, fr[0][kt], a0a);
      a1a = mfma16(hf, fr[1][kt], a1a);
    }
    #pragma unroll
    for (int kt = 4; kt < 8; ++kt) {
      bf16x8 hf = *(const bf16x8*)&hbc[kt * 32 + quad * 8];
      a0b = mfma16(hf, fr[0][kt], a0b);
      a1b = mfma16(hf, fr[1][kt], a1b);
    }
    f32x4 ac0 = a0a + a0b, ac1 = a1a + a1b;
    // rv via intra-wave shuffles (producing wave == consuming wave):
    float rv[8];
    #pragma unroll
    for (int j = 0; j < 8; ++j) {
      int c = quad * 8 + j;
      float v0 = __shfl(ac0[0], c & 15, 64);
      float v1 = __shfl(ac1[0], c & 15, 64);
      rv[j] = (c < 16) ? v0 : v1;
    }
    // S2: rh A-frag slice (mts, kf)
    {
      bf16x8 aW = *(const bf16x8*)&hbc[kf * 32 + quad * 8];
      bf16x8 rh;
      #pragma unroll
      for (int j = 0; j < 8; ++j)
        rh[j] = (__bf16)(sigmoid_f((float)xf_c[j] + rv[j]) * (float)aW[j]);
      *(bf16x8*)&fragbuf[mts * 4096 + (kf * 64 + lane) * 8] = rh;
    }
    ldsbar();  // bar_B: fragbuf visible
    // prefetch next chunk's xr/xh (consumed next iteration)
    bf16x8 xf_n;
    bf16x4 xh_n[2];
    {
      int ctn = (ct + 1) & 15;
      xf_n = *(const bf16x8*)(xrb + (size_t)(2 * ctn + mts) * 4096 + ((size_t)kf * 64 + lane) * 8);
      #pragma unroll
      for (int mt = 0; mt < 2; ++mt)
        xh_n[mt] = *(const bf16x4*)(xhb + ((size_t)(2 * ctn + mt) * 16 + w) * 256 + lane * 4);
    }
    // S3: HH = rh @ rkh for BOTH M-tiles at this wave's col group nt=w
    // (2 independent chains of 8; 1 rkh read + 2 fragbuf reads per kt)
    f32x4 aH0 = z, aH1 = z;
    #pragma unroll
    for (int kt = 0; kt < 8; ++kt) {
      bf16x8 fw = *(const bf16x8*)&rkh_lds[(((size_t)kt * 16 + w) * 64 + lane) * 8];
      bf16x8 am0 = *(const bf16x8*)&fragbuf[(kt * 64 + lane) * 8];
      bf16x8 am1 = *(const bf16x8*)&fragbuf[4096 + (kt * 64 + lane) * 8];
      aH0 = mfma16(am0, fw, aH0);
      aH1 = mfma16(am1, fw, aH1);
    }
    // blend all 32 rows for own cols: h_end = pt*h + sum_s aw[s]*tanh(...)_s
    const float* awp = &aw_lds[ct * 32];
    f32x4 wq0 = *(const f32x4*)&awp[quad * 4];
    f32x4 wq1 = *(const f32x4*)&awp[16 + quad * 4];
    float Pt = pt_lds[ct];
    float part = 0.f;
    #pragma unroll
    for (int r = 0; r < 4; ++r) {
      part += wq0[r] * tanh_f((float)xh_c[0][r] + aH0[r]);
      part += wq1[r] * tanh_f((float)xh_c[1][r] + aH1[r]);
    }
    part += __shfl_xor(part, 16, 64);
    part += __shfl_xor(part, 32, 64);
    float hn = Pt * hs + part;
    hs = hn;
    if (quad == 0)         // ping-pong write (bf16) — target not being read
      hbn[w * 16 + col] = (__bf16)hn;
    ldsbar();  // bar_D: new h visible; fragbuf free
    { bf16_t* t = hbc; hbc = hbn; hbn = t; }
    xf_c = xf_n;
    xh_c[0] = xh_n[0];
    xh_c[1] = xh_n[1];
  }
  // hbc now holds the episode vector (bf16)

  // phase D: memory = relu([mem, episode, q] @ Wm + bm); wave w -> nt=w
  {
    f32x4 am_a = (f32x4){0.f,0.f,0.f,0.f}, am_b = am_a;
    const bf16_t* wmb = ws + E_WMF;
    #pragma unroll
    for (int kt = 0; kt < 24; ++kt) {
      bf16x8 a;
      if (kt >= 8 && kt < 16) {           // episode: already bf16, broadcast read
        a = *(const bf16x8*)&hbc[(kt - 8) * 32 + quad * 8];
      } else {
        const float* sv = (kt < 8) ? &mem_lds[kt * 32] : &q_lds[(kt - 16) * 32];
        const f32x4* vp = (const f32x4*)&sv[quad * 8];
        f32x4 va = vp[0], vb = vp[1];
        #pragma unroll
        for (int j = 0; j < 4; ++j) { a[j] = (__bf16)va[j]; a[4 + j] = (__bf16)vb[j]; }
      }
      bf16x8 bf = *(const bf16x8*)(wmb + (((size_t)kt * 16 + w) * 64 + lane) * 8);
      if (kt & 1) am_b = mfma16(a, bf, am_b);
      else        am_a = mfma16(a, bf, am_a);
    }
    if (quad == 0) {
      int v = w * 16 + col;
      float r = fmaxf(am_a[0] + am_b[0] + bm_lds[v], 0.f);
      mem_ws[(size_t)b * 256 + v] = r;
      if (last) out[(size_t)b * 256 + v] = r;
    }
  }
}

extern "C" void kernel_launch(void* const* d_in, const int* in_sizes, int n_in,
                              void* d_out, int out_size, void* d_ws, size_t ws_size,
                              hipStream_t stream) {
  (void)in_sizes; (void)n_in; (void)out_size; (void)ws_size;
  const float* facts    = (const float*)d_in[0];
  const float* question = (const float*)d_in[1];
  const float* W1       = (const float*)d_in[2];
  const float* b1       = (const float*)d_in[3];
  const float* W2       = (const float*)d_in[4];
  const float* b2       = (const float*)d_in[5];
  const float* gru_k    = (const float*)d_in[6];
  const float* gru_rk   = (const float*)d_in[7];
  const float* gru_b    = (const float*)d_in[8];
  const float* Wm       = (const float*)d_in[9];
  const float* bm       = (const float*)d_in[10];
  bf16_t* ws = (bf16_t*)d_ws;
  float* fws = (float*)(ws + E_END);
  float* scores_ws = fws + F_SCORES;
  float* mem_ws    = fws + F_MEM;
  float* pfix_ws   = fws + F_PFIX;
  float* out = (float*)d_out;

  prep_weights<<<2048, 256, 0, stream>>>(gru_k, gru_rk, W1, Wm, ws);
  // xproj now also emits pfix and episode-0 scores (fused scores_fixed tail)
  xproj_kernel<<<dim3(128, 8), 512, 0, stream>>>(facts, question, gru_b,
                                                 b1, W2, b2, ws, mem_ws,
                                                 pfix_ws, scores_ws);
  for (int ep = 0; ep < 3; ++ep) {
    scan_kernel<<<128, 1024, 0, stream>>>(question, bm, ws, scores_ws, mem_ws, out, ep == 2);
    if (ep < 2)
      scores_kernel<<<dim3(128, 8), 256, 0, stream>>>(W2, b2, ws, mem_ws, pfix_ws, scores_ws);
  }
}

// Round 15
// 392.894 us; speedup vs baseline: 1.0059x; 1.0059x over previous
//
#include <hip/hip_runtime.h>
#include <cstdint>
#include <cstddef>

// ---------------------------------------------------------------------------
// Episodic memory module (DMN) on MI355X — round 21.
//
// R20 post-mortem: fusion mechanically clean (VGPR 64, no spill, absmax
// exact) but economically a wash — "scores_fixed=48us" was an unmeasured
// estimate (really ~26); xproj grew 22.  Total pinned at 392-395 across 5
// structurally different configs; ~40us of launch-gap overhead smears
// small wins.  R20 kept (one fewer launch).
//
// R21: algebraic VALU cut in scores_kernel (ep1/ep2).  (f.m)@W1b ==
// f@(diag(m)W1b), and B-frag k-index == A-frag k-index ((lane>>4)*8+j),
// so wf1m[j]=bf16(mv[j]*wf1[j]) built ONCE per kt replaces the a1 build
// done per (kt,mt): fragment builds 8->5 per kt (-37% of dominant VALU).
// f8 feeds the MFMA directly.  pfix/ep0 path untouched (bit-identical).
// Numerics: rounds m*W1 instead of f*m to bf16 — same magnitude.
// Predictions: absmax <= ~0.0156 (tripwire: fail -> revert), scores
// -15-25%, total ~383-390.
// ---------------------------------------------------------------------------

typedef __bf16 bf16_t;
typedef __attribute__((ext_vector_type(8))) __bf16 bf16x8;
typedef __attribute__((ext_vector_type(4))) __bf16 bf16x4;
typedef __attribute__((ext_vector_type(4))) float f32x4;

static __device__ __forceinline__ f32x4 mfma16(bf16x8 a, bf16x8 b, f32x4 c) {
  return __builtin_amdgcn_mfma_f32_16x16x32_bf16(a, b, c, 0, 0, 0);
}
static __device__ __forceinline__ float fast_rcp(float x) { return __builtin_amdgcn_rcpf(x); }
static __device__ __forceinline__ float sigmoid_f(float x) {
  return fast_rcp(1.f + exp2f(-1.44269504f * x));
}
static __device__ __forceinline__ float tanh_f(float x) {
  float e = exp2f(2.88539008f * x);
  return 1.f - 2.f * fast_rcp(e + 1.f);
}
static __device__ __forceinline__ unsigned short f2bf(float x) {
  __bf16 h = (__bf16)x;
  return __builtin_bit_cast(unsigned short, h);
}
// Workgroup barrier WITHOUT the vmcnt(0) drain __syncthreads() carries.
// All call sites are in wave-uniform control flow.
static __device__ __forceinline__ void ldsbar() {
  asm volatile("s_waitcnt lgkmcnt(0)\n\ts_barrier" ::: "memory");
}
// Opaque pin: value becomes an asm output — cannot be rematerialized or its
// defining load sunk past this point.  Zero instructions emitted.
static __device__ __forceinline__ void pin_frag(bf16x8& v) {
  f32x4 t = __builtin_bit_cast(f32x4, v);
  asm volatile("" : "+v"(t));
  v = __builtin_bit_cast(bf16x8, t);
}

// ws layout (bf16 element offsets).  B-fragment layout for a K x N matrix:
// elem(k,n) at ((kt*NT + nt)*64 + lane)*8 + j, kt=k/32, nt=n/16,
// lane=((k%32)/8)*16 + (n%16), j=k%8.
static constexpr size_t E_GRUK  = 0;                            // K=256 N=512
static constexpr size_t E_RKR   = 131072;                       // K=256 N=256
static constexpr size_t E_RKH   = 196608;
static constexpr size_t E_W1F   = 262144;                       // K=1024 N=64
static constexpr size_t E_WMF   = 327680;                       // K=768 N=256
static constexpr size_t E_XR    = 524288;                       // + b*131072 (A-frag)
static constexpr size_t E_XHC   = E_XR  + (size_t)128 * 131072; // + b*131072 (C order)
static constexpr size_t E_FACTS = E_XHC + (size_t)128 * 131072; // + b*131072 (A-frag)
static constexpr size_t E_END   = E_FACTS + (size_t)128 * 131072;
static constexpr size_t F_SCORES = 0;
static constexpr size_t F_MEM    = 65536;
static constexpr size_t F_PFIX   = 131072;   // 128*32*4*64 f32x4 = 4M floats

__global__ void prep_weights(const float* __restrict__ gru_k,
                             const float* __restrict__ gru_rk,
                             const float* __restrict__ W1,
                             const float* __restrict__ Wm,
                             bf16_t* __restrict__ ws) {
  size_t idx = (size_t)blockIdx.x * 256 + threadIdx.x;
  if (idx >= 524288) return;
  size_t local; int NT, which;
  if (idx < 131072)      { local = idx;          NT = 32; which = 0; }
  else if (idx < 196608) { local = idx - 131072; NT = 16; which = 1; }
  else if (idx < 262144) { local = idx - 196608; NT = 16; which = 2; }
  else if (idx < 327680) { local = idx - 262144; NT = 4;  which = 3; }
  else                   { local = idx - 327680; NT = 16; which = 4; }
  int j    = (int)(local & 7);
  int lane = (int)((local >> 3) & 63);
  size_t rem = local >> 9;
  int nt = (int)(rem % NT);
  int kt = (int)(rem / NT);
  int k = kt * 32 + (lane >> 4) * 8 + j;
  int n = nt * 16 + (lane & 15);
  float v;
  switch (which) {
    case 0:  v = gru_k[(size_t)k * 768 + 256 + n]; break;
    case 1:  v = gru_rk[(size_t)k * 768 + 256 + n]; break;
    case 2:  v = gru_rk[(size_t)k * 768 + 512 + n]; break;
    case 3:  v = (n < 50) ? W1[(size_t)k * 50 + n] : 0.f; break;
    default: v = Wm[(size_t)k * 256 + n]; break;
  }
  ws[idx] = (__bf16)v;
}

// ------------------------------- kernel A ----------------------------------
// x_proj = facts[b] @ gru_k[:,U:3U] + bias; persists facts bf16 A-frags;
// fused scores_fixed tail — pfix (q-terms + b1 in C-frag order) AND
// episode-0 scores (mem==question at ep0) for rows [64s,64s+64).
// grid (b=128, s=8), 512 threads (8 waves).  Main loop unchanged from R8.
// (512,4): allocator-compatible optimum — VGPR 64, no spills.
__global__ __launch_bounds__(512, 4)
void xproj_kernel(const float* __restrict__ facts,
                  const float* __restrict__ question,
                  const float* __restrict__ gru_bg,
                  const float* __restrict__ b1g,
                  const float* __restrict__ W2g,
                  const float* __restrict__ b2g,
                  bf16_t* __restrict__ ws,
                  float* __restrict__ mem_ws,
                  float* __restrict__ pfix,
                  float* __restrict__ scores_ws) {
  const int b = blockIdx.x, s = blockIdx.y;
  const int tid = threadIdx.x, w = tid >> 6, lane = tid & 63;
  const int quad = lane >> 4, col = lane & 15;
  __shared__ float grub[512];
  __shared__ float q_lds[256], b1_lds[64], W2_lds[64], score_lds[64];
  __shared__ float b2s;
  __shared__ bf16_t fragbuf[8192];   // 2 tiles; logical unit u at u^kt (swizzled)
  __shared__ bf16_t xrtrans[8192];   // 2 tiles; logical unit u at u^((u>>4)&3)
  grub[tid] = gru_bg[256 + tid];     // [0,256)=xr bias, [256,512)=xh bias
  if (tid < 256) q_lds[tid] = question[(size_t)b * 256 + tid];
  if (tid < 64) {
    b1_lds[tid] = (tid < 50) ? b1g[tid] : 0.f;
    W2_lds[tid] = (tid < 50) ? W2g[tid] : 0.f;
  }
  if (tid == 0) b2s = b2g[0];
  if (s == 0 && tid < 256) mem_ws[b * 256 + tid] = question[(size_t)b * 256 + tid];
  __syncthreads();

  bf16_t* xr_ws = ws + E_XR   + (size_t)b * 131072;
  bf16_t* xh_ws = ws + E_XHC  + (size_t)b * 131072;
  bf16_t* ff_ws = ws + E_FACTS + (size_t)b * 131072;
  const bf16_t* gbase = ws + E_GRUK;
  // staging ownership: 512 threads cover 2 tiles x 16 rows x 16 col-segs
  const int tile = tid >> 8, row = (tid >> 4) & 15, cseg = tid & 15;

  // this thread's two swizzled fragbuf deposit units (constant across iters)
  int wunit[2];
  #pragma unroll
  for (int half = 0; half < 2; ++half) {
    int u0 = cseg * 16 + half * 8;
    int kt = u0 >> 5, qk = (u0 >> 3) & 3;
    int u = kt * 64 + qk * 16 + row;
    wunit[half] = tile * 512 + (u ^ kt);
  }

  for (int it = 0; it < 2; ++it) {
    const int Mt0 = s * 4 + 2 * it;
    // stage this thread's 16 facts floats (one tile each; 512 thr = 2 tiles)
    float v[16];
    {
      const float* src = facts + (((size_t)b * 512) + (Mt0 + tile) * 16 + row) * 256 + cseg * 16;
      #pragma unroll
      for (int i = 0; i < 4; ++i) {
        f32x4 t4 = ((const f32x4*)src)[i];
        v[4*i] = t4[0]; v[4*i+1] = t4[1]; v[4*i+2] = t4[2]; v[4*i+3] = t4[3];
      }
    }
    #pragma unroll
    for (int half = 0; half < 2; ++half) {
      bf16x8 pk;
      #pragma unroll
      for (int j = 0; j < 8; ++j) pk[j] = (__bf16)v[half * 8 + j];
      *(bf16x8*)&fragbuf[wunit[half] * 8] = pk;
    }
    ldsbar();  // bar1: fragbuf visible
    { // persist facts frags for scores (unswizzle -> ws holds logical layout)
      #pragma unroll
      for (int e = 0; e < 2; ++e) {
        int p = 2 * tid + e;
        int t = p >> 9, pu = p & 511;
        int qu = pu ^ (pu >> 6);
        bf16x8 f = *(bf16x8*)&fragbuf[(t * 512 + qu) * 8];
        *(bf16x8*)(ff_ws + (size_t)(Mt0 + t) * 4096 + (size_t)pu * 8) = f;
      }
    }
    // paired MFMA: each gk fragment load feeds BOTH A-tiles; wave owns nt=4
    f32x4 acc[2][4];
    #pragma unroll
    for (int t = 0; t < 2; ++t)
      #pragma unroll
      for (int nt = 0; nt < 4; ++nt) acc[t][nt] = (f32x4){0.f, 0.f, 0.f, 0.f};
    #pragma unroll
    for (int kt = 0; kt < 8; ++kt) {
      int us = (kt * 64 + lane) ^ kt;
      bf16x8 af0 = *(const bf16x8*)&fragbuf[(size_t)us * 8];
      bf16x8 af1 = *(const bf16x8*)&fragbuf[(size_t)(512 + us) * 8];
      #pragma unroll
      for (int nt = 0; nt < 4; ++nt) {
        bf16x8 g = *(const bf16x8*)(gbase + (((size_t)kt * 32 + (w * 4 + nt)) * 64 + lane) * 8);
        acc[0][nt] = mfma16(af0, g, acc[0][nt]);
        acc[1][nt] = mfma16(af1, g, acc[1][nt]);
      }
    }
    // epilogue: waves 0-3 -> xr (transpose via swizzled LDS), 4-7 -> xh
    #pragma unroll
    for (int t = 0; t < 2; ++t)
      #pragma unroll
      for (int nt = 0; nt < 4; ++nt) {
        int o = w * 64 + nt * 16 + col;
        float bias = grub[o];
        if (o < 256) { // wave-uniform: w < 4
          int ktA = o >> 5, qkA = (o >> 3) & 3, j = o & 7;
          #pragma unroll
          for (int r = 0; r < 4; ++r) {
            int u = ktA * 64 + qkA * 16 + (quad * 4 + r);
            int us2 = u ^ ((u >> 4) & 3);
            xrtrans[(t * 512 + us2) * 8 + j] = (__bf16)(acc[t][nt][r] + bias);
          }
        } else {       // wave-uniform: w >= 4
          int ntx = (o >> 4) - 16;
          unsigned short s0 = f2bf(acc[t][nt][0] + bias), s1 = f2bf(acc[t][nt][1] + bias);
          unsigned short s2 = f2bf(acc[t][nt][2] + bias), s3 = f2bf(acc[t][nt][3] + bias);
          uint2 pv;
          pv.x = (unsigned)s0 | ((unsigned)s1 << 16);
          pv.y = (unsigned)s2 | ((unsigned)s3 << 16);
          *(uint2*)(xh_ws + ((size_t)(Mt0 + t) * 16 + ntx) * 256 + lane * 4) = pv;
        }
      }
    ldsbar();  // bar2: xrtrans visible
    { // xr store: read swizzled, write logical (ws layout unchanged for scan)
      #pragma unroll
      for (int e = 0; e < 2; ++e) {
        int p = 2 * tid + e;
        int t = p >> 9, pu = p & 511;
        int qu = pu ^ ((pu >> 4) & 3);
        bf16x8 f = *(bf16x8*)&xrtrans[(t * 512 + qu) * 8];
        *(bf16x8*)(xr_ws + (size_t)(Mt0 + t) * 4096 + (size_t)pu * 8) = f;
      }
    }
    // no bar3: next iteration's bar1 orders xrtrans reads vs next writes.
  }

  // ---- fused scores_fixed tail: pfix + ep0 scores for rows [64s,64s+64) ---
  // Wave w: col-tile ntq=w&3, local M-tiles {mtL0, mtL0+1} with mtL0=(w>>2)*2.
  // Formula bit-identical to the old scores_fixed kernel (same f8 from ff_ws,
  // same q, same W1 frags): pfix = accq+b1; ep0 score = tanh(pfix+accm)*W2.
  __syncthreads();              // drains vmcnt: ff_ws stores from ALL waves
  if (tid < 64) score_lds[tid] = b2s;
  ldsbar();                     // score_lds init visible before atomics
  {
    const int ntq = w & 3;
    const int mtL0 = (w >> 2) * 2;
    const bf16_t* ffb = ff_ws + (size_t)(s * 4 + mtL0) * 4096;
    const bf16_t* w1b = ws + E_W1F;

    f32x4 accq[2], accm[2];
    #pragma unroll
    for (int m2 = 0; m2 < 2; ++m2) {
      accq[m2] = (f32x4){0.f, 0.f, 0.f, 0.f};
      accm[m2] = (f32x4){0.f, 0.f, 0.f, 0.f};
    }
    #pragma unroll 2
    for (int kt = 0; kt < 8; ++kt) {
      bf16x8 wf0 = *(const bf16x8*)(w1b + (((size_t)(kt)      * 4 + ntq) * 64 + lane) * 8);
      bf16x8 wf1 = *(const bf16x8*)(w1b + (((size_t)(8  + kt) * 4 + ntq) * 64 + lane) * 8);
      bf16x8 wf2 = *(const bf16x8*)(w1b + (((size_t)(16 + kt) * 4 + ntq) * 64 + lane) * 8);
      bf16x8 wf3 = *(const bf16x8*)(w1b + (((size_t)(24 + kt) * 4 + ntq) * 64 + lane) * 8);
      const f32x4* qp = (const f32x4*)&q_lds[kt * 32 + quad * 8];
      f32x4 qa = qp[0], qb = qp[1];
      float qv[8] = {qa[0],qa[1],qa[2],qa[3],qb[0],qb[1],qb[2],qb[3]};
      #pragma unroll
      for (int m2 = 0; m2 < 2; ++m2) {
        bf16x8 f8 = *(const bf16x8*)(ffb + (size_t)m2 * 4096 + (kt * 64 + lane) * 8);
        bf16x8 a0, a2;
        #pragma unroll
        for (int j = 0; j < 8; ++j) {
          float fu = (float)f8[j];
          a0[j] = (__bf16)(fu * qv[j]);
          a2[j] = (__bf16)fabsf(fu - qv[j]);
        }
        accq[m2] = mfma16(a0, wf0, accq[m2]);
        accq[m2] = mfma16(a2, wf2, accq[m2]);
        accm[m2] = mfma16(a0, wf1, accm[m2]);
        accm[m2] = mfma16(a2, wf3, accm[m2]);
      }
    }
    int hcol = ntq * 16 + col;
    float pb1 = b1_lds[hcol], pw2 = W2_lds[hcol];
    f32x4* po = (f32x4*)pfix;
    #pragma unroll
    for (int m2 = 0; m2 < 2; ++m2) {
      // pfix = q-terms + b1 (the later-episode accumulator seed)
      f32x4 o = accq[m2];
      #pragma unroll
      for (int r = 0; r < 4; ++r) o[r] += pb1;
      po[(((size_t)b * 32 + s * 4 + mtL0 + m2) * 4 + ntq) * 64 + lane] = o;
      // ep0 score partial: tanh(pfix + m-terms) * W2  (mem==q at ep0)
      float p[4];
      #pragma unroll
      for (int r = 0; r < 4; ++r) p[r] = tanh_f(o[r] + accm[m2][r]) * pw2;
      #pragma unroll
      for (int r = 0; r < 4; ++r) {
        p[r] += __shfl_xor(p[r], 1, 64);
        p[r] += __shfl_xor(p[r], 2, 64);
        p[r] += __shfl_xor(p[r], 4, 64);
        p[r] += __shfl_xor(p[r], 8, 64);
      }
      if (col == 0) {
        #pragma unroll
        for (int r = 0; r < 4; ++r)
          atomicAdd(&score_lds[(mtL0 + m2) * 16 + quad * 4 + r], p[r]);
      }
    }
  }
  ldsbar();                     // all atomics done
  if (tid < 64) scores_ws[(size_t)b * 512 + s * 64 + tid] = score_lds[tid];
}

// ------------------------------- kernel B ----------------------------------
// scores[b, n] for episodes 1,2: m-terms only on top of P_fixed.
// grid (b=128, s=8); WG does rows [64s,64s+64).
// R21: (f.m)@W1b == f@(diag(m)W1b); B-frag k-index == A-frag k-index, so
// wf1m[j]=bf16(mv[j]*wf1[j]) ONCE per kt replaces the per-mt a1 build
// (fragment builds 8->5 per kt).  f8 is the MFMA A operand directly.
__global__ __launch_bounds__(256)
void scores_kernel(const float* __restrict__ W2g,
                   const float* __restrict__ b2g,
                   const bf16_t* __restrict__ ws,
                   const float* __restrict__ mem_ws,
                   const float* __restrict__ pfix,
                   float* __restrict__ scores_ws) {
  const int b = blockIdx.x, s = blockIdx.y;
  const int tid = threadIdx.x, w = tid >> 6, lane = tid & 63;
  const int quad = lane >> 4, col = lane & 15;
  __shared__ float mem_lds[256], W2_lds[64], score_lds[64];
  __shared__ float b2s;
  mem_lds[tid] = mem_ws[(size_t)b * 256 + tid];
  if (tid < 64) W2_lds[tid] = (tid < 50) ? W2g[tid] : 0.f;
  if (tid == 0) b2s = b2g[0];
  __syncthreads();
  if (tid < 64) score_lds[tid] = b2s;
  __syncthreads();

  const bf16_t* ffb = ws + E_FACTS + (size_t)b * 131072 + (size_t)s * 4 * 4096;
  const bf16_t* w1b = ws + E_W1F;
  const f32x4* pf = (const f32x4*)pfix;

  f32x4 acc[4];
  #pragma unroll
  for (int mt = 0; mt < 4; ++mt)
    acc[mt] = pf[(((size_t)b * 32 + s * 4 + mt) * 4 + w) * 64 + lane];

  #pragma unroll 2
  for (int kt = 0; kt < 8; ++kt) {
    bf16x8 wf1 = *(const bf16x8*)(w1b + (((size_t)(8  + kt) * 4 + w) * 64 + lane) * 8);
    bf16x8 wf3 = *(const bf16x8*)(w1b + (((size_t)(24 + kt) * 4 + w) * 64 + lane) * 8);
    const f32x4* mp = (const f32x4*)&mem_lds[kt * 32 + quad * 8];
    f32x4 ma = mp[0], mb = mp[1];
    float mv[8] = {ma[0],ma[1],ma[2],ma[3],mb[0],mb[1],mb[2],mb[3]};
    // premultiplied weight fragment: wf1m[k,n] = bf16(m[k] * W1b[k,n]);
    // B-frag k-index (lane>>4)*8+j matches mv's indexing.
    bf16x8 wf1m;
    #pragma unroll
    for (int j = 0; j < 8; ++j) wf1m[j] = (__bf16)(mv[j] * (float)wf1[j]);
    #pragma unroll
    for (int mt = 0; mt < 4; ++mt) {
      bf16x8 f8 = *(const bf16x8*)(ffb + (size_t)mt * 4096 + (kt * 64 + lane) * 8);
      bf16x8 a3;
      #pragma unroll
      for (int j = 0; j < 8; ++j)
        a3[j] = (__bf16)fabsf((float)f8[j] - mv[j]);
      acc[mt] = mfma16(f8, wf1m, acc[mt]);
      acc[mt] = mfma16(a3, wf3, acc[mt]);
    }
  }
  int hcol = w * 16 + col;
  float pw2 = W2_lds[hcol];
  #pragma unroll
  for (int mt = 0; mt < 4; ++mt) {
    float p[4];
    #pragma unroll
    for (int r = 0; r < 4; ++r) p[r] = tanh_f(acc[mt][r]) * pw2;
    #pragma unroll
    for (int r = 0; r < 4; ++r) {
      p[r] += __shfl_xor(p[r], 1, 64);
      p[r] += __shfl_xor(p[r], 2, 64);
      p[r] += __shfl_xor(p[r], 4, 64);
      p[r] += __shfl_xor(p[r], 8, 64);
    }
    if (col == 0) {
      #pragma unroll
      for (int r = 0; r < 4; ++r)
        atomicAdd(&score_lds[mt * 16 + quad * 4 + r], p[r]);
    }
  }
  __syncthreads();
  if (tid < 64) scores_ws[(size_t)b * 512 + s * 64 + tid] = score_lds[tid];
}

// ------------------------------- kernel C ----------------------------------
// softmax + chunked-Picard attn-GRU scan (T=32, 16 chunks) + memory update.
// 128 WGs x 1024 threads (16 waves = 4/SIMD).
// R19 roles: S1/S2 by (kf=w>>1, mts=w&1); S3/blend by OUTPUT COLUMN nt=w —
// wave computes BOTH M-tiles for cols [16w,16w+16), owns h cols end-to-end.
// 2 barriers/chunk.  R16 (kept): waves_per_eu(4,4) + asm pin on fr.
__global__
__attribute__((amdgpu_flat_work_group_size(1024, 1024), amdgpu_waves_per_eu(4, 4)))
void scan_kernel(const float* __restrict__ question,
                 const float* __restrict__ bmg,
                 const bf16_t* __restrict__ ws,
                 const float* __restrict__ scores_ws,
                 float* __restrict__ mem_ws,
                 float* __restrict__ out,
                 int last) {
  const int b = blockIdx.x;
  const int tid = threadIdx.x, w = tid >> 6, lane = tid & 63;
  const int quad = lane >> 4, col = lane & 15;
  const int kf = w >> 1, mts = w & 1;   // S1/S2 roles; S3/blend role: nt = w

  __shared__ bf16_t hb_lds[512];        // bf16 h ping-pong [0,256) / [256,512)
  __shared__ float aw_lds[512], pt_lds[16];
  __shared__ float q_lds[256], mem_lds[256], bm_lds[256], red[16];
  __shared__ bf16_t fragbuf[8192];      // rh A-frags, 2 M-tiles x 4096
  __shared__ bf16_t rkh_lds[65536];     // rkh B-frags, 128KB, staged once

  // stage rkh frags global->LDS, stride-1 per lane (conflict-free, coalesced)
  // 8192 bf16x8 units / 1024 threads = 8 iterations.
  {
    const bf16x8* srcw = (const bf16x8*)(ws + E_RKH);
    bf16x8* dstw = (bf16x8*)rkh_lds;
    #pragma unroll
    for (int i = 0; i < 8; ++i)
      dstw[(size_t)i * 1024 + tid] = srcw[(size_t)i * 1024 + tid];
  }

  if (tid < 256) {
    q_lds[tid]   = question[(size_t)b * 256 + tid];
    mem_lds[tid] = mem_ws[(size_t)b * 256 + tid];
    bm_lds[tid]  = bmg[tid];
  }
  if (tid < 512) hb_lds[tid] = (__bf16)0.f;

  // softmax over 512 scores: waves 0-7 (tid<512) do the work, barriers global
  float s0 = 0.f, e0 = 0.f;
  if (tid < 512) {
    s0 = scores_ws[(size_t)b * 512 + tid];
    float mx = s0;
    #pragma unroll
    for (int o = 32; o > 0; o >>= 1) mx = fmaxf(mx, __shfl_xor(mx, o, 64));
    if (lane == 0) red[w] = mx;
  }
  __syncthreads();
  if (tid < 512) {
    float gmax = red[0];
    #pragma unroll
    for (int i = 1; i < 8; ++i) gmax = fmaxf(gmax, red[i]);
    e0 = __expf(s0 - gmax);
    float sm = e0;
    #pragma unroll
    for (int o = 32; o > 0; o >>= 1) sm += __shfl_xor(sm, o, 64);
    if (lane == 0) red[8 + w] = sm;
  }
  __syncthreads();
  if (tid < 512) {
    float tot = red[8];
    #pragma unroll
    for (int i = 9; i < 16; ++i) tot += red[i];
    aw_lds[tid] = e0 * fast_rcp(tot);
  }
  ldsbar();
  // per-chunk (T=32) blend weights in place:
  // aw[s] := a_s * prod_{j>s in chunk}(1-a_j),  pt[ct] := prod(1-a) over chunk
  if (tid < 16) {
    float av[32];
    #pragma unroll
    for (int j = 0; j < 32; ++j) av[j] = aw_lds[tid * 32 + j];
    float suf = 1.f;
    #pragma unroll
    for (int j = 31; j >= 0; --j) {
      aw_lds[tid * 32 + j] = av[j] * suf;
      suf *= (1.f - av[j]);
    }
    pt_lds[tid] = suf;
  }
  ldsbar();  // also covers rkh_lds staging visibility (lgkmcnt drains ds_writes)

  // S1 recurrence weights: kf owns rkr out-cols [32kf, 32kf+32); 64 VGPR.
  // Duplicated across the mts pair (both waves run S1).  Pinned in registers
  // via opaque asm so the loads cannot be sunk into the chunk loop.
  const bf16_t* xrb = ws + E_XR  + (size_t)b * 131072;
  const bf16_t* xhb = ws + E_XHC + (size_t)b * 131072;
  bf16x8 fr[2][8];
  {
    const bf16_t* rb = ws + E_RKR;
    #pragma unroll
    for (int nt_ = 0; nt_ < 2; ++nt_)
      #pragma unroll
      for (int kt = 0; kt < 8; ++kt) {
        size_t off = (((size_t)kt * 16 + (kf * 2 + nt_)) * 64 + lane) * 8;
        fr[nt_][kt] = *(const bf16x8*)(rb + off);
      }
    #pragma unroll
    for (int nt_ = 0; nt_ < 2; ++nt_)
      #pragma unroll
      for (int kt = 0; kt < 8; ++kt)
        pin_frag(fr[nt_][kt]);
  }
  // chunk-0 xr (A-frag of tile mts, fragment kf) and xh (C order, both mt,
  // ntx = w — this wave's output col group)
  bf16x8 xf_c;
  bf16x4 xh_c[2];
  xf_c = *(const bf16x8*)(xrb + (size_t)mts * 4096 + ((size_t)kf * 64 + lane) * 8);
  #pragma unroll
  for (int mt = 0; mt < 2; ++mt)
    xh_c[mt] = *(const bf16x4*)(xhb + ((size_t)mt * 16 + w) * 256 + lane * 4);

  bf16_t* hbc = &hb_lds[0];
  bf16_t* hbn = &hb_lds[256];
  float hs = 0.f;  // exact fp32 self-copy of this wave's h cols [16w,16w+16)

  for (int ct = 0; ct < 16; ++ct) {
    // S1: rv0 = h @ rkr (both mts waves duplicate).  Split-K 2 chains of 4.
    f32x4 z = (f32x4){0.f,0.f,0.f,0.f};
    f32x4 a0a = z, a0b = z, a1a = z, a1b = z;
    #pragma unroll
    for (int kt = 0; kt < 4; ++kt) {
      bf16x8 hf = *(const bf16x8*)&hbc[kt * 32 + quad * 8];
      a0a = mfma16(hf, fr[0][kt], a0a);
      a1a = mfma16(hf, fr[1][kt], a1a);
    }
    #pragma unroll
    for (int kt = 4; kt < 8; ++kt) {
      bf16x8 hf = *(const bf16x8*)&hbc[kt * 32 + quad * 8];
      a0b = mfma16(hf, fr[0][kt], a0b);
      a1b = mfma16(hf, fr[1][kt], a1b);
    }
    f32x4 ac0 = a0a + a0b, ac1 = a1a + a1b;
    // rv via intra-wave shuffles (producing wave == consuming wave):
    float rv[8];
    #pragma unroll
    for (int j = 0; j < 8; ++j) {
      int c = quad * 8 + j;
      float v0 = __shfl(ac0[0], c & 15, 64);
      float v1 = __shfl(ac1[0], c & 15, 64);
      rv[j] = (c < 16) ? v0 : v1;
    }
    // S2: rh A-frag slice (mts, kf)
    {
      bf16x8 aW = *(const bf16x8*)&hbc[kf * 32 + quad * 8];
      bf16x8 rh;
      #pragma unroll
      for (int j = 0; j < 8; ++j)
        rh[j] = (__bf16)(sigmoid_f((float)xf_c[j] + rv[j]) * (float)aW[j]);
      *(bf16x8*)&fragbuf[mts * 4096 + (kf * 64 + lane) * 8] = rh;
    }
    ldsbar();  // bar_B: fragbuf visible
    // prefetch next chunk's xr/xh (consumed next iteration)
    bf16x8 xf_n;
    bf16x4 xh_n[2];
    {
      int ctn = (ct + 1) & 15;
      xf_n = *(const bf16x8*)(xrb + (size_t)(2 * ctn + mts) * 4096 + ((size_t)kf * 64 + lane) * 8);
      #pragma unroll
      for (int mt = 0; mt < 2; ++mt)
        xh_n[mt] = *(const bf16x4*)(xhb + ((size_t)(2 * ctn + mt) * 16 + w) * 256 + lane * 4);
    }
    // S3: HH = rh @ rkh for BOTH M-tiles at this wave's col group nt=w
    // (2 independent chains of 8; 1 rkh read + 2 fragbuf reads per kt)
    f32x4 aH0 = z, aH1 = z;
    #pragma unroll
    for (int kt = 0; kt < 8; ++kt) {
      bf16x8 fw = *(const bf16x8*)&rkh_lds[(((size_t)kt * 16 + w) * 64 + lane) * 8];
      bf16x8 am0 = *(const bf16x8*)&fragbuf[(kt * 64 + lane) * 8];
      bf16x8 am1 = *(const bf16x8*)&fragbuf[4096 + (kt * 64 + lane) * 8];
      aH0 = mfma16(am0, fw, aH0);
      aH1 = mfma16(am1, fw, aH1);
    }
    // blend all 32 rows for own cols: h_end = pt*h + sum_s aw[s]*tanh(...)_s
    const float* awp = &aw_lds[ct * 32];
    f32x4 wq0 = *(const f32x4*)&awp[quad * 4];
    f32x4 wq1 = *(const f32x4*)&awp[16 + quad * 4];
    float Pt = pt_lds[ct];
    float part = 0.f;
    #pragma unroll
    for (int r = 0; r < 4; ++r) {
      part += wq0[r] * tanh_f((float)xh_c[0][r] + aH0[r]);
      part += wq1[r] * tanh_f((float)xh_c[1][r] + aH1[r]);
    }
    part += __shfl_xor(part, 16, 64);
    part += __shfl_xor(part, 32, 64);
    float hn = Pt * hs + part;
    hs = hn;
    if (quad == 0)         // ping-pong write (bf16) — target not being read
      hbn[w * 16 + col] = (__bf16)hn;
    ldsbar();  // bar_D: new h visible; fragbuf free
    { bf16_t* t = hbc; hbc = hbn; hbn = t; }
    xf_c = xf_n;
    xh_c[0] = xh_n[0];
    xh_c[1] = xh_n[1];
  }
  // hbc now holds the episode vector (bf16)

  // phase D: memory = relu([mem, episode, q] @ Wm + bm); wave w -> nt=w
  {
    f32x4 am_a = (f32x4){0.f,0.f,0.f,0.f}, am_b = am_a;
    const bf16_t* wmb = ws + E_WMF;
    #pragma unroll
    for (int kt = 0; kt < 24; ++kt) {
      bf16x8 a;
      if (kt >= 8 && kt < 16) {           // episode: already bf16, broadcast read
        a = *(const bf16x8*)&hbc[(kt - 8) * 32 + quad * 8];
      } else {
        const float* sv = (kt < 8) ? &mem_lds[kt * 32] : &q_lds[(kt - 16) * 32];
        const f32x4* vp = (const f32x4*)&sv[quad * 8];
        f32x4 va = vp[0], vb = vp[1];
        #pragma unroll
        for (int j = 0; j < 4; ++j) { a[j] = (__bf16)va[j]; a[4 + j] = (__bf16)vb[j]; }
      }
      bf16x8 bf = *(const bf16x8*)(wmb + (((size_t)kt * 16 + w) * 64 + lane) * 8);
      if (kt & 1) am_b = mfma16(a, bf, am_b);
      else        am_a = mfma16(a, bf, am_a);
    }
    if (quad == 0) {
      int v = w * 16 + col;
      float r = fmaxf(am_a[0] + am_b[0] + bm_lds[v], 0.f);
      mem_ws[(size_t)b * 256 + v] = r;
      if (last) out[(size_t)b * 256 + v] = r;
    }
  }
}

extern "C" void kernel_launch(void* const* d_in, const int* in_sizes, int n_in,
                              void* d_out, int out_size, void* d_ws, size_t ws_size,
                              hipStream_t stream) {
  (void)in_sizes; (void)n_in; (void)out_size; (void)ws_size;
  const float* facts    = (const float*)d_in[0];
  const float* question = (const float*)d_in[1];
  const float* W1       = (const float*)d_in[2];
  const float* b1       = (const float*)d_in[3];
  const float* W2       = (const float*)d_in[4];
  const float* b2       = (const float*)d_in[5];
  const float* gru_k    = (const float*)d_in[6];
  const float* gru_rk   = (const float*)d_in[7];
  const float* gru_b    = (const float*)d_in[8];
  const float* Wm       = (const float*)d_in[9];
  const float* bm       = (const float*)d_in[10];
  bf16_t* ws = (bf16_t*)d_ws;
  float* fws = (float*)(ws + E_END);
  float* scores_ws = fws + F_SCORES;
  float* mem_ws    = fws + F_MEM;
  float* pfix_ws   = fws + F_PFIX;
  float* out = (float*)d_out;

  prep_weights<<<2048, 256, 0, stream>>>(gru_k, gru_rk, W1, Wm, ws);
  // xproj also emits pfix and episode-0 scores (fused scores_fixed tail)
  xproj_kernel<<<dim3(128, 8), 512, 0, stream>>>(facts, question, gru_b,
                                                 b1, W2, b2, ws, mem_ws,
                                                 pfix_ws, scores_ws);
  for (int ep = 0; ep < 3; ++ep) {
    scan_kernel<<<128, 1024, 0, stream>>>(question, bm, ws, scores_ws, mem_ws, out, ep == 2);
    if (ep < 2)
      scores_kernel<<<dim3(128, 8), 256, 0, stream>>>(W2, b2, ws, mem_ws, pfix_ws, scores_ws);
  }
}